// Round 6
// baseline (401.814 us; speedup 1.0000x reference)
//
#include <hip/hip_runtime.h>

#define IN_F   8192
#define OUT_F  8192
#define HALF_F 4096
#define STAGES 13

#define KCHUNK 128              // qweight rows per GEMV block
#define NCHUNK (IN_F / KCHUNK)  // 64 k-chunks
#define OTILE  1024             // outputs per GEMV block (256 threads x 4)

#define PF_BLOCKS 96            // L2-prefetch blocks in kernel 1
#define PF_ITERS  16            // 1024 thr * 16 * 16 B = 256 KiB per block

// clang-native vector types (HIP's int4/float4 are structs, which
// __builtin_nontemporal_load rejects)
typedef int   v4i __attribute__((ext_vector_type(4)));
typedef float v4f __attribute__((ext_vector_type(4)));

// ---------------------------------------------------------------------------
// Kernel 1 (1 + PF_BLOCKS blocks x 1024):
//   block 0     : h = butterfly_V(x / scaleWH) + sum(h)  (single-CU serial path)
//   blocks 1..96: stream the first 24 MiB of qweight through L2 (plain loads,
//                 lines allocate) so the GEMV's earliest chunks hit L2.
//                 Overlaps the ~10 us butterfly; no communication between the
//                 two roles, so no coherence hazard.
// Stage semantics (reference einsum + interleave):
//   out[m]        =  c*in[2m] + s*in[2m+1]
//   out[n/2 + m]  = -s*in[2m] + c*in[2m+1]
// __sincosf (hw v_sin/v_cos): angles in [0,2pi]; measured absmax 0.0156 vs
// threshold 3.8.
// ---------------------------------------------------------------------------
__global__ __launch_bounds__(1024) void butterfly_in_kernel(
    const float* __restrict__ x, const float* __restrict__ scaleWH,
    const float* __restrict__ V_angles, const int* __restrict__ pin,
    const int* __restrict__ pout, float* __restrict__ h_out,
    float* __restrict__ sum_out, const int* __restrict__ q,
    int* __restrict__ scratch)
{
    const int tid = threadIdx.x;

    if (blockIdx.x != 0) {
        // ---- qweight L2 prefetch ----
        const int pf = blockIdx.x - 1;
        const int* base = q + (size_t)pf * (1024 * PF_ITERS * 4);
        int acc = 0;
#pragma unroll
        for (int it = 0; it < PF_ITERS; ++it) {
            v4i v = *(const v4i*)(base + (it * 1024 + tid) * 4);
            acc ^= v[0] ^ v[1] ^ v[2] ^ v[3];
        }
        if (tid == 0) scratch[pf] = acc;   // keep loads live
        return;
    }

    // ---- block 0: V butterfly ----
    __shared__ float bufA[IN_F];
    __shared__ float bufB[IN_F];

#pragma unroll
    for (int j = 0; j < 8; ++j) {
        int k = tid + j * 1024;
        int src = pin[k];
        bufA[k] = x[src] / scaleWH[src];
    }
    __syncthreads();

    float* in = bufA;
    float* out = bufB;
    for (int s = 0; s < STAGES; ++s) {
        const float* ang = V_angles + s * HALF_F;
#pragma unroll
        for (int j = 0; j < 4; ++j) {
            int m = tid + j * 1024;          // stride-1 writes, stride-2 reads
            float c, sn;
            __sincosf(ang[m], &sn, &c);
            float x0 = in[2 * m];
            float x1 = in[2 * m + 1];
            out[m]          =  c * x0 + sn * x1;
            out[HALF_F + m] = -sn * x0 + c * x1;
        }
        __syncthreads();
        float* t = in; in = out; out = t;
    }

    float local = 0.0f;
#pragma unroll
    for (int j = 0; j < 8; ++j) {
        int k = tid + j * 1024;
        float v = in[pout[k]];
        h_out[k] = v;
        local += v;
    }
    __syncthreads();
    float* red = out;                         // reuse the spare LDS buffer
    red[tid] = local;
    __syncthreads();
    for (int s = 512; s > 0; s >>= 1) {
        if (tid < s) red[tid] += red[tid + s];
        __syncthreads();
    }
    if (tid == 0) *sum_out = red[0];
}

// ---------------------------------------------------------------------------
// Kernel 2: partials[kc][o] = sum_{i in chunk kc} q[i][o] * h[i]
// No atomics; each (kc,o) cell written once, coalesced. qweight (IN_F,OUT_F)
// row-major; v4i nontemporal loads = 16 B/lane coalesced (256 MiB stream —
// nt skips L2 allocation but still probes it, so the prefetched chunks hit).
// Memory-bound: floor ~40 us at 6.7 TB/s.
// ---------------------------------------------------------------------------
__global__ __launch_bounds__(256) void gemv_kernel(
    const int* __restrict__ q, const float* __restrict__ h,
    float* __restrict__ partials)
{
    __shared__ float hs[KCHUNK];
    const int tid = threadIdx.x;
    const int ot = blockIdx.x;    // output tile  [0, OUT_F/OTILE)
    const int kc = blockIdx.y;    // k chunk      [0, NCHUNK)
    const int i0 = kc * KCHUNK;

    if (tid < KCHUNK) hs[tid] = h[i0 + tid];
    __syncthreads();

    const int o = ot * OTILE + tid * 4;
    const int* qp = q + (size_t)i0 * OUT_F + o;

    float a0 = 0.f, a1 = 0.f, a2 = 0.f, a3 = 0.f;
#pragma unroll 4
    for (int ii = 0; ii < KCHUNK; ++ii) {
        v4i v = __builtin_nontemporal_load((const v4i*)qp);
        qp += OUT_F;
        float hv = hs[ii];
        a0 += hv * (float)v[0];
        a1 += hv * (float)v[1];
        a2 += hv * (float)v[2];
        a3 += hv * (float)v[3];
    }
    v4f r; r[0] = a0; r[1] = a1; r[2] = a2; r[3] = a3;
    *(v4f*)(partials + (size_t)kc * OUT_F + o) = r;
}

// ---------------------------------------------------------------------------
// Kernel 2b: t[o] = scale*((2/15)*sum_kc partials[kc][o] - sum_h)
// 32 blocks x 256 threads; lane-consecutive o -> fully coalesced reads of the
// 2 MiB partial matrix. Dequant affine folded in here (saves an LDS pass in
// kernel 3).
// ---------------------------------------------------------------------------
__global__ __launch_bounds__(256) void reduce_kernel(
    const float* __restrict__ partials, const float* __restrict__ sum_h_p,
    const float* __restrict__ scale_p, float* __restrict__ t_out)
{
    const int o = blockIdx.x * 256 + threadIdx.x;
    float s = 0.0f;
#pragma unroll 8
    for (int c = 0; c < NCHUNK; ++c) s += partials[(size_t)c * OUT_F + o];
    t_out[o] = (*scale_p) * ((2.0f / 15.0f) * s - (*sum_h_p));
}

// ---------------------------------------------------------------------------
// Kernel 3: out = butterfly_U(t) + bias   (t already dequant-corrected)
// ---------------------------------------------------------------------------
__global__ __launch_bounds__(1024) void butterfly_out_kernel(
    const float* __restrict__ t, const float* __restrict__ bias,
    const float* __restrict__ U_angles, const int* __restrict__ pin,
    const int* __restrict__ pout, float* __restrict__ out_f)
{
    __shared__ float bufA[OUT_F];
    __shared__ float bufB[OUT_F];
    const int tid = threadIdx.x;

#pragma unroll
    for (int j = 0; j < 8; ++j) {
        int k = tid + j * 1024;
        bufB[k] = t[pin[k]];                  // gather straight from global (L2-hot)
    }
    __syncthreads();

    float* in = bufB;
    float* out = bufA;
    for (int s = 0; s < STAGES; ++s) {
        const float* ang = U_angles + s * HALF_F;
#pragma unroll
        for (int j = 0; j < 4; ++j) {
            int m = tid + j * 1024;
            float c, sn;
            __sincosf(ang[m], &sn, &c);
            float x0 = in[2 * m];
            float x1 = in[2 * m + 1];
            out[m]          =  c * x0 + sn * x1;
            out[HALF_F + m] = -sn * x0 + c * x1;
        }
        __syncthreads();
        float* tp = in; in = out; out = tp;
    }

#pragma unroll
    for (int j = 0; j < 8; ++j) {
        int k = tid + j * 1024;
        out_f[k] = in[pout[k]] + bias[k];
    }
}

// ---------------------------------------------------------------------------
extern "C" void kernel_launch(void* const* d_in, const int* in_sizes, int n_in,
                              void* d_out, int out_size, void* d_ws, size_t ws_size,
                              hipStream_t stream) {
    const float* x        = (const float*)d_in[0];
    const int*   qweight  = (const int*)  d_in[1];
    const float* scaleWH  = (const float*)d_in[2];
    const float* scale    = (const float*)d_in[3];
    const float* bias     = (const float*)d_in[4];
    const float* U_angles = (const float*)d_in[5];
    const float* V_angles = (const float*)d_in[6];
    const int*   pU_in    = (const int*)  d_in[7];
    const int*   pU_out   = (const int*)  d_in[8];
    const int*   pV_in    = (const int*)  d_in[9];
    const int*   pV_out   = (const int*)  d_in[10];
    float* out = (float*)d_out;

    // ws layout: h[8192] | sum_h[8] | t[8192] | partials[64*8192] | scratch
    float* h        = (float*)d_ws;
    float* sum_h    = h + IN_F;
    float* t        = sum_h + 8;
    float* partials = t + OUT_F;
    int*   scratch  = (int*)(partials + (size_t)NCHUNK * OUT_F);

    butterfly_in_kernel<<<1 + PF_BLOCKS, 1024, 0, stream>>>(
        x, scaleWH, V_angles, pV_in, pV_out, h, sum_h, qweight, scratch);

    gemv_kernel<<<dim3(OUT_F / OTILE, NCHUNK), 256, 0, stream>>>(
        qweight, h, partials);

    reduce_kernel<<<OUT_F / 256, 256, 0, stream>>>(partials, sum_h, scale, t);

    butterfly_out_kernel<<<1, 1024, 0, stream>>>(
        t, bias, U_angles, pU_in, pU_out, out);
}

// Round 7
// 399.810 us; speedup vs baseline: 1.0050x; 1.0050x over previous
//
#include <hip/hip_runtime.h>

#define IN_F   8192
#define OUT_F  8192
#define HALF_F 4096
#define STAGES 13

#define KCHUNK 64               // qweight rows per GEMV block (1024 blocks -> 4/CU)
#define NCHUNK (IN_F / KCHUNK)  // 128 k-chunks
#define OTILE  1024             // outputs per GEMV block (256 threads x 4)

// clang-native vector types (HIP's int4/float4 are structs, which
// __builtin_nontemporal_load rejects)
typedef int   v4i __attribute__((ext_vector_type(4)));
typedef float v4f __attribute__((ext_vector_type(4)));

// ---------------------------------------------------------------------------
// Kernel 1: h = butterfly_V(x / scaleWH), plus sum(h). Single block, 1024 thr.
// Stage semantics (reference einsum + interleave):
//   out[m]        =  c*in[2m] + s*in[2m+1]
//   out[n/2 + m]  = -s*in[2m] + c*in[2m+1]
// __sincosf (hw v_sin/v_cos): angles in [0,2pi]; measured absmax ~0.016-0.06
// vs threshold 3.8. (R5 u-table precompute and R6 L2 prefetch both measured
// neutral-to-negative — keep this kernel minimal.)
// ---------------------------------------------------------------------------
__global__ __launch_bounds__(1024) void butterfly_in_kernel(
    const float* __restrict__ x, const float* __restrict__ scaleWH,
    const float* __restrict__ V_angles, const int* __restrict__ pin,
    const int* __restrict__ pout, float* __restrict__ h_out,
    float* __restrict__ sum_out)
{
    __shared__ float bufA[IN_F];
    __shared__ float bufB[IN_F];
    const int tid = threadIdx.x;

#pragma unroll
    for (int j = 0; j < 8; ++j) {
        int k = tid + j * 1024;
        int src = pin[k];
        bufA[k] = x[src] / scaleWH[src];
    }
    __syncthreads();

    float* in = bufA;
    float* out = bufB;
    for (int s = 0; s < STAGES; ++s) {
        const float* ang = V_angles + s * HALF_F;
#pragma unroll
        for (int j = 0; j < 4; ++j) {
            int m = tid + j * 1024;          // stride-1 writes, stride-2 reads
            float c, sn;
            __sincosf(ang[m], &sn, &c);
            float x0 = in[2 * m];
            float x1 = in[2 * m + 1];
            out[m]          =  c * x0 + sn * x1;
            out[HALF_F + m] = -sn * x0 + c * x1;
        }
        __syncthreads();
        float* t = in; in = out; out = t;
    }

    float local = 0.0f;
#pragma unroll
    for (int j = 0; j < 8; ++j) {
        int k = tid + j * 1024;
        float v = in[pout[k]];
        h_out[k] = v;
        local += v;
    }
    __syncthreads();
    float* red = out;                         // reuse the spare LDS buffer
    red[tid] = local;
    __syncthreads();
    for (int s = 512; s > 0; s >>= 1) {
        if (tid < s) red[tid] += red[tid + s];
        __syncthreads();
    }
    if (tid == 0) *sum_out = red[0];
}

// ---------------------------------------------------------------------------
// Kernel 2: partials[kc][o] = sum_{i in chunk kc} q[i][o] * h[i]
// No atomics; each (kc,o) cell written once, coalesced. qweight (IN_F,OUT_F)
// row-major; v4i nontemporal loads = 16 B/lane coalesced (256 MiB pure
// stream — keep it out of L2). 1024 blocks = 4/CU for latency hiding.
// Memory-bound floor ~40 us at 6.7 TB/s — this dispatch IS the roofline.
// ---------------------------------------------------------------------------
__global__ __launch_bounds__(256) void gemv_kernel(
    const int* __restrict__ q, const float* __restrict__ h,
    float* __restrict__ partials)
{
    __shared__ float hs[KCHUNK];
    const int tid = threadIdx.x;
    const int ot = blockIdx.x;    // output tile  [0, OUT_F/OTILE)
    const int kc = blockIdx.y;    // k chunk      [0, NCHUNK)
    const int i0 = kc * KCHUNK;

    if (tid < KCHUNK) hs[tid] = h[i0 + tid];
    __syncthreads();

    const int o = ot * OTILE + tid * 4;
    const int* qp = q + (size_t)i0 * OUT_F + o;

    float a0 = 0.f, a1 = 0.f, a2 = 0.f, a3 = 0.f;
#pragma unroll 4
    for (int ii = 0; ii < KCHUNK; ++ii) {
        v4i v = __builtin_nontemporal_load((const v4i*)qp);
        qp += OUT_F;
        float hv = hs[ii];
        a0 += hv * (float)v[0];
        a1 += hv * (float)v[1];
        a2 += hv * (float)v[2];
        a3 += hv * (float)v[3];
    }
    v4f r; r[0] = a0; r[1] = a1; r[2] = a2; r[3] = a3;
    *(v4f*)(partials + (size_t)kc * OUT_F + o) = r;
}

// ---------------------------------------------------------------------------
// Kernel 2b: t[o] = scale*((2/15)*sum_kc partials[kc][o] - sum_h)
// 32 blocks x 256 threads; lane-consecutive o -> fully coalesced reads of the
// 4 MiB partial matrix. Dequant affine folded in (saves an LDS pass in k3).
// ---------------------------------------------------------------------------
__global__ __launch_bounds__(256) void reduce_kernel(
    const float* __restrict__ partials, const float* __restrict__ sum_h_p,
    const float* __restrict__ scale_p, float* __restrict__ t_out)
{
    const int o = blockIdx.x * 256 + threadIdx.x;
    float s = 0.0f;
#pragma unroll 8
    for (int c = 0; c < NCHUNK; ++c) s += partials[(size_t)c * OUT_F + o];
    t_out[o] = (*scale_p) * ((2.0f / 15.0f) * s - (*sum_h_p));
}

// ---------------------------------------------------------------------------
// Kernel 3: out = butterfly_U(t) + bias   (t already dequant-corrected)
// ---------------------------------------------------------------------------
__global__ __launch_bounds__(1024) void butterfly_out_kernel(
    const float* __restrict__ t, const float* __restrict__ bias,
    const float* __restrict__ U_angles, const int* __restrict__ pin,
    const int* __restrict__ pout, float* __restrict__ out_f)
{
    __shared__ float bufA[OUT_F];
    __shared__ float bufB[OUT_F];
    const int tid = threadIdx.x;

#pragma unroll
    for (int j = 0; j < 8; ++j) {
        int k = tid + j * 1024;
        bufB[k] = t[pin[k]];                  // gather straight from global (L2-hot)
    }
    __syncthreads();

    float* in = bufB;
    float* out = bufA;
    for (int s = 0; s < STAGES; ++s) {
        const float* ang = U_angles + s * HALF_F;
#pragma unroll
        for (int j = 0; j < 4; ++j) {
            int m = tid + j * 1024;
            float c, sn;
            __sincosf(ang[m], &sn, &c);
            float x0 = in[2 * m];
            float x1 = in[2 * m + 1];
            out[m]          =  c * x0 + sn * x1;
            out[HALF_F + m] = -sn * x0 + c * x1;
        }
        __syncthreads();
        float* tp = in; in = out; out = tp;
    }

#pragma unroll
    for (int j = 0; j < 8; ++j) {
        int k = tid + j * 1024;
        out_f[k] = in[pout[k]] + bias[k];
    }
}

// ---------------------------------------------------------------------------
extern "C" void kernel_launch(void* const* d_in, const int* in_sizes, int n_in,
                              void* d_out, int out_size, void* d_ws, size_t ws_size,
                              hipStream_t stream) {
    const float* x        = (const float*)d_in[0];
    const int*   qweight  = (const int*)  d_in[1];
    const float* scaleWH  = (const float*)d_in[2];
    const float* scale    = (const float*)d_in[3];
    const float* bias     = (const float*)d_in[4];
    const float* U_angles = (const float*)d_in[5];
    const float* V_angles = (const float*)d_in[6];
    const int*   pU_in    = (const int*)  d_in[7];
    const int*   pU_out   = (const int*)  d_in[8];
    const int*   pV_in    = (const int*)  d_in[9];
    const int*   pV_out   = (const int*)  d_in[10];
    float* out = (float*)d_out;

    // ws layout: h[8192] | sum_h[8] | t[8192] | partials[128*8192]
    float* h        = (float*)d_ws;
    float* sum_h    = h + IN_F;
    float* t        = sum_h + 8;
    float* partials = t + OUT_F;

    butterfly_in_kernel<<<1, 1024, 0, stream>>>(
        x, scaleWH, V_angles, pV_in, pV_out, h, sum_h);

    gemv_kernel<<<dim3(OUT_F / OTILE, NCHUNK), 256, 0, stream>>>(
        qweight, h, partials);

    reduce_kernel<<<OUT_F / 256, 256, 0, stream>>>(partials, sum_h, scale, t);

    butterfly_out_kernel<<<1, 1024, 0, stream>>>(
        t, bias, U_angles, pU_in, pU_out, out);
}